// Round 2
// baseline (106.647 us; speedup 1.0000x reference)
//
#include <hip/hip_runtime.h>
#include <math.h>

// Levinson-Durbin, one thread per batch.
// Compact-code formulation: carry a[] and its reversal b[] so every array
// index in the m-loop body is a compile-time constant (register-resident),
// while the outer loop over m stays a runtime loop (~1.6 KB body, I$-resident).
//
//   b_{m}[i] = a_m[m-i]  (b[m]=1 boundary carried in-array)
//   acc_m    = sum_{i=1..M} b_{m-1}[i-1] * r[i]   (zeros beyond order m => exact)
//   k        = -acc / E
//   a[i]    += k * b[i-1];  b[i] = b_old[i-1] + k * a_old[i];  b[0] = k
//   E       *= (1 - k^2)

constexpr int M  = 64;
constexpr int EL = M + 1;   // 65 floats per row
constexpr int BT = 64;      // one wave per block

__global__ __launch_bounds__(BT, 1) void levinson_kernel(const float* __restrict__ rin,
                                                         float* __restrict__ out,
                                                         int B) {
  __shared__ float smem[BT * EL];   // 16,640 B
  const int tid = threadIdx.x;
  const int b0  = blockIdx.x * BT;
  const int nb  = min(BT, B - b0);
  const int nf  = nb * EL;
  const size_t base = (size_t)b0 * EL;

  // ---- coalesced stage-in: global float4 -> LDS ----
  {
    const int n4 = nf >> 2;
    const float4* in4 = reinterpret_cast<const float4*>(rin + base); // 16B aligned
    float4* s4 = reinterpret_cast<float4*>(smem);
    for (int i = tid; i < n4; i += BT) s4[i] = in4[i];
    for (int i = (n4 << 2) + tid; i < nf; i += BT) smem[i] = rin[base + i];
  }
  __syncthreads();

  float K = 0.f;
  float A[EL];          // A[1..M] live
  if (tid < nb) {
    float r[EL];
#pragma unroll
    for (int i = 0; i < EL; ++i) r[i] = smem[tid * EL + i];  // stride-65: conflict-free

    float Bb[M];        // reversed coeffs, b[0..M-1]
#pragma unroll
    for (int i = 0; i < EL; ++i) A[i] = 0.f;
#pragma unroll
    for (int i = 0; i < M; ++i) Bb[i] = 0.f;
    Bb[0] = 1.f;        // b_0[0] = a[0] = 1
    float E = r[0];

#pragma unroll 1
    for (int m = 1; m <= M; ++m) {
      // acc = sum_{i=1..M} Bb[i-1]*r[i]  (includes the r[m] boundary term via b[m-1]=1)
      float s0 = 0.f, s1 = 0.f, s2 = 0.f, s3 = 0.f;
#pragma unroll
      for (int i = 1; i <= M; i += 4) {
        s0 = fmaf(Bb[i - 1], r[i],     s0);
        s1 = fmaf(Bb[i],     r[i + 1], s1);
        s2 = fmaf(Bb[i + 1], r[i + 2], s2);
        s3 = fmaf(Bb[i + 2], r[i + 3], s3);
      }
      const float acc = (s0 + s1) + (s2 + s3);
      const float k = -acc / E;           // IEEE divide (precision)

      // joint update, descending i so Bb[i-1] reads are pre-overwrite
      A[M] = fmaf(k, Bb[M - 1], A[M]);
#pragma unroll
      for (int i = M - 1; i >= 1; --i) {
        const float tA = A[i], tb = Bb[i - 1];
        A[i]  = fmaf(k, tb, tA);
        Bb[i] = fmaf(k, tA, tb);
      }
      Bb[0] = k;
      E = fmaf(-k * k, E, E);             // E *= (1 - k^2)
    }
    K = sqrtf(E);
  }

  if (tid < nb) {
    smem[tid * EL] = K;
#pragma unroll
    for (int j = 1; j <= M; ++j) smem[tid * EL + j] = A[j];
  }
  __syncthreads();

  // ---- coalesced stage-out: LDS -> global float4 ----
  {
    const int n4 = nf >> 2;
    const float4* s4 = reinterpret_cast<const float4*>(smem);
    float4* out4 = reinterpret_cast<float4*>(out + base);
    for (int i = tid; i < n4; i += BT) out4[i] = s4[i];
    for (int i = (n4 << 2) + tid; i < nf; i += BT) out[base + i] = smem[i];
  }
}

extern "C" void kernel_launch(void* const* d_in, const int* in_sizes, int n_in,
                              void* d_out, int out_size, void* d_ws, size_t ws_size,
                              hipStream_t stream) {
  const float* r = (const float*)d_in[0];
  float* out = (float*)d_out;
  const int B = in_sizes[0] / EL;          // 65536
  const int blocks = (B + BT - 1) / BT;    // 1024
  levinson_kernel<<<blocks, BT, 0, stream>>>(r, out, B);
}

// Round 3
// 101.053 us; speedup vs baseline: 1.0554x; 1.0554x over previous
//
#include <hip/hip_runtime.h>
#include <math.h>

// Levinson-Durbin, 4 lanes per batch (blocked split of the reversed-vector form).
//   lane s of a 4-lane group holds, for j = 0..15:
//     rr[j] = r[16s+1+j],  aa[j] = A[16s+1+j],  bb[j] = Bb[16s+j]
//   dot   : acc = sum_i Bb[i-1]*r[i]  -> sum_j bb[j]*rr[j]   (lane-local, xor-butterfly reduce)
//   A upd : A[i] += k*Bb[i-1]         -> aa[j] = fma(k, bb[j], aa[j])   (lane-local)
//   B upd : Bb[i] = Bb[i-1] + k*A[i]  -> bb[j] = fma(k, aa[j-1], bb[j-1]), with the
//           j=0 term needing prev lane's (bb[15], aa[15]) via 2x shfl_up; s==0 gets k.
//   E *= (1 - k^2);  K = sqrt(E).

constexpr int M    = 64;
constexpr int EL   = M + 1;        // 65 floats per row
constexpr int LPB  = 4;            // lanes per batch
constexpr int NJ   = M / LPB;      // 16 elements per lane
constexpr int BT   = 256;          // threads per block
constexpr int ROWS = BT / LPB;     // 64 batches per block

__global__ __launch_bounds__(BT, 4) void levinson_kernel(const float* __restrict__ rin,
                                                         float* __restrict__ out,
                                                         int B) {
  __shared__ float smem[ROWS * EL];   // 16,640 B
  const int tid = threadIdx.x;
  const int b0  = blockIdx.x * ROWS;
  if (b0 >= B) return;
  const int nf  = ROWS * EL;          // B=65536 divides exactly into 1024 full blocks
  const size_t base = (size_t)b0 * EL;

  // ---- coalesced stage-in: global float4 -> LDS ----
  {
    const int n4 = nf >> 2;           // 1040, exact
    const float4* in4 = reinterpret_cast<const float4*>(rin + base);  // 16B aligned
    float4* s4 = reinterpret_cast<float4*>(smem);
    for (int i = tid; i < n4; i += BT) s4[i] = in4[i];
  }
  __syncthreads();

  const int row = tid >> 2;           // local batch
  const int s   = tid & 3;            // sub-lane within batch
  const float* rrow = &smem[row * EL];

  float rr[NJ], aa[NJ], bb[NJ];
#pragma unroll
  for (int j = 0; j < NJ; ++j) rr[j] = rrow[16 * s + 1 + j];
#pragma unroll
  for (int j = 0; j < NJ; ++j) { aa[j] = 0.f; bb[j] = 0.f; }
  if (s == 0) bb[0] = 1.f;            // b_0 = delta_0
  float E = rrow[0];

#pragma unroll 1
  for (int m = 1; m <= M; ++m) {
    // partial dot, 4 accumulators for ILP
    float p0 = 0.f, p1 = 0.f, p2 = 0.f, p3 = 0.f;
#pragma unroll
    for (int j = 0; j < NJ; j += 4) {
      p0 = fmaf(bb[j],     rr[j],     p0);
      p1 = fmaf(bb[j + 1], rr[j + 1], p1);
      p2 = fmaf(bb[j + 2], rr[j + 2], p2);
      p3 = fmaf(bb[j + 3], rr[j + 3], p3);
    }
    float acc = (p0 + p1) + (p2 + p3);
    acc += __shfl_xor(acc, 1);        // xor-butterfly within 4-lane group:
    acc += __shfl_xor(acc, 2);        // all 4 lanes hold the full sum
    const float k = -acc / E;         // IEEE divide (precision), redundant per lane

    // previous lane's trailing elements (old values), before any overwrite
    const float pbb = __shfl_up(bb[NJ - 1], 1);
    const float paa = __shfl_up(aa[NJ - 1], 1);

    // descending joint update; reads of [j-1] happen before step j-1 writes them
#pragma unroll
    for (int j = NJ - 1; j >= 1; --j) {
      const float t = bb[j];
      bb[j] = fmaf(k, aa[j - 1], bb[j - 1]);
      aa[j] = fmaf(k, t, aa[j]);
    }
    {
      const float t = bb[0];
      bb[0] = (s == 0) ? k : fmaf(k, paa, pbb);   // Bb[0]=k; Bb[16s]=Bb_old[16s-1]+k*A_old[16s]
      aa[0] = fmaf(k, t, aa[0]);
    }
    E = fmaf(-k * k, E, E);           // E *= (1 - k^2)
  }

  __syncthreads();                    // input no longer needed; reuse smem for output

  {
    float* orow = &smem[row * EL];
    if (s == 0) orow[0] = sqrtf(E);
#pragma unroll
    for (int j = 0; j < NJ; ++j) orow[16 * s + 1 + j] = aa[j];
  }
  __syncthreads();

  // ---- coalesced stage-out: LDS -> global float4 ----
  {
    const int n4 = nf >> 2;
    const float4* s4 = reinterpret_cast<const float4*>(smem);
    float4* out4 = reinterpret_cast<float4*>(out + base);
    for (int i = tid; i < n4; i += BT) out4[i] = s4[i];
  }
}

extern "C" void kernel_launch(void* const* d_in, const int* in_sizes, int n_in,
                              void* d_out, int out_size, void* d_ws, size_t ws_size,
                              hipStream_t stream) {
  const float* r = (const float*)d_in[0];
  float* out = (float*)d_out;
  const int B = in_sizes[0] / EL;            // 65536
  const int blocks = (B + ROWS - 1) / ROWS;  // 1024
  levinson_kernel<<<blocks, BT, 0, stream>>>(r, out, B);
}